// Round 12
// baseline (1130.543 us; speedup 1.0000x reference)
//
#include <hip/hip_runtime.h>
#include <hip/hip_fp16.h>

typedef _Float16 half2_t __attribute__((ext_vector_type(2)));
typedef unsigned int u32;

// ---------------- problem dims ----------------
constexpr int Bn = 64, Sn = 256, Ln = 9;
constexpr int G4H = 1024;   // 4*H

// ---------------- workspace layout (bytes) ----------------
constexpr size_t XZ_OFF   = 0;                                  // [2][64][256][1024] f32
constexpr size_t XZ_BYTES = (size_t)2 * Bn * Sn * G4H * 4;      // 128 MB
constexpr size_t H_OFF    = XZ_OFF + XZ_BYTES;                  // [64][256][512] f32 (fwd|bwd)
constexpr size_t H_BYTES  = (size_t)Bn * Sn * 512 * 4;          // 32 MB
constexpr size_t UPK_OFF  = H_OFF + H_BYTES;                    // [2][32][1024] u32 (pairs 0..31)
constexpr size_t UPK_BYTES= (size_t)2 * 32 * G4H * 4;           // 256 KB
constexpr size_t USTR_OFF = UPK_OFF + UPK_BYTES;                // [2][6][4][1024] uint4 (pairs 32..127)
constexpr size_t USTR_BYTES = (size_t)2 * 6 * 4 * 1024 * 16;    // 768 KB

// ---------------- helpers ----------------
__device__ __forceinline__ float sigf(float x) {
  return __fdividef(1.0f, 1.0f + __expf(-x));
}
__device__ __forceinline__ float tanhf_fast(float x) {
  x = fminf(fmaxf(x, -15.0f), 15.0f);
  float e = __expf(-2.0f * x);
  return __fdividef(1.0f - e, 1.0f + e);
}

#if __has_builtin(__builtin_amdgcn_fdot2)
__device__ __forceinline__ float FDOT2(half2_t a, half2_t b, float c) {
  return __builtin_amdgcn_fdot2(a, b, c, false);
}
#else
__device__ __forceinline__ float FDOT2(half2_t a, half2_t b, float c) {
  return c + (float)a.x * (float)b.x + (float)a.y * (float)b.y;
}
#endif

__device__ __forceinline__ half2_t H2(u32 w) { return __builtin_bit_cast(half2_t, w); }

// ---------------- kernel 1: pack U ----------------
// pairs 0..31  -> upk[dir][kp][col]            (for LDS staging)
// pairs 32..127-> ustr[dir][c][q][col].e       (chunk c=(kp-32)/16, q=((kp-32)/4)%4,
//                                               e=(kp-32)%4; uint4-per-col, coalesced)
__global__ void pack_u(const float* __restrict__ Uf, const float* __restrict__ Ub,
                       u32* __restrict__ upk, u32* __restrict__ ustr) {
  int idx = blockIdx.x * 256 + threadIdx.x;      // [2][128][1024]
  if (idx >= 2 * 128 * 1024) return;
  int d  = idx >> 17;
  int kp = (idx >> 10) & 127;
  int j  = idx & 1023;
  const float* U = d ? Ub : Uf;
  _Float16 a = (_Float16)U[(size_t)(2 * kp) * 1024 + j];
  _Float16 b = (_Float16)U[(size_t)(2 * kp + 1) * 1024 + j];
  u32 pa = (u32)__builtin_bit_cast(unsigned short, a);
  u32 pb = (u32)__builtin_bit_cast(unsigned short, b);
  u32 v = pa | (pb << 16);
  if (kp < 32) {
    upk[((size_t)d * 32 + kp) * 1024 + j] = v;
  } else {
    int r = kp - 32;
    int c = r >> 4, q = (r >> 2) & 3, e = r & 3;
    ustr[((((size_t)d * 6 + c) * 4 + q) * 1024 + j) * 4 + e] = v;
  }
}

// ---------------- kernel 2: xz = gather(emb) @ [Wf|Wb] + bias ----------------
__global__ __launch_bounds__(256, 4)
void xz_gemm(const int* __restrict__ tok, const float* __restrict__ emb,
             const float* __restrict__ Wf, const float* __restrict__ biasf,
             const float* __restrict__ Wb, const float* __restrict__ biasb,
             float* __restrict__ xz) {
  __shared__ float As[32][64];
  __shared__ float Bs[32][128];
  __shared__ int toks[64];
  const int tid = threadIdx.x;
  const int mt = blockIdx.x, nt = blockIdx.y;
  const int d = nt >> 3;
  const float* W    = d ? Wb : Wf;
  const float* bias = d ? biasb : biasf;
  const int n0 = (nt & 7) * 128;
  const int r0 = mt * 64;
  if (tid < 64) toks[tid] = tok[r0 + tid];
  __syncthreads();
  const int tr = tid >> 4, tc = tid & 15;
  float acc[4][8];
#pragma unroll
  for (int j = 0; j < 8; ++j) {
    float bv = bias[n0 + tc * 8 + j];
#pragma unroll
    for (int i = 0; i < 4; ++i) acc[i][j] = bv;
  }
  const int ai = tid >> 2, kq = tid & 3;
  const int kb = tid >> 3, fb = tid & 7;
  for (int k0 = 0; k0 < 256; k0 += 32) {
    const float* ar = emb + (size_t)toks[ai] * 256 + k0 + kq * 8;
    float4 a0 = *(const float4*)ar;
    float4 a1 = *(const float4*)(ar + 4);
    As[kq * 8 + 0][ai] = a0.x; As[kq * 8 + 1][ai] = a0.y;
    As[kq * 8 + 2][ai] = a0.z; As[kq * 8 + 3][ai] = a0.w;
    As[kq * 8 + 4][ai] = a1.x; As[kq * 8 + 5][ai] = a1.y;
    As[kq * 8 + 6][ai] = a1.z; As[kq * 8 + 7][ai] = a1.w;
    const float* wr = W + (size_t)(k0 + kb) * 1024 + n0;
#pragma unroll
    for (int q = 0; q < 4; ++q)
      *(float4*)&Bs[kb][(fb + 8 * q) * 4] = *(const float4*)(wr + (fb + 8 * q) * 4);
    __syncthreads();
#pragma unroll
    for (int kk = 0; kk < 32; ++kk) {
      float4 a4 = *(const float4*)&As[kk][tr * 4];
      float4 b0 = *(const float4*)&Bs[kk][tc * 8];
      float4 b1 = *(const float4*)&Bs[kk][tc * 8 + 4];
      float av[4] = {a4.x, a4.y, a4.z, a4.w};
      float bv[8] = {b0.x, b0.y, b0.z, b0.w, b1.x, b1.y, b1.z, b1.w};
#pragma unroll
      for (int i = 0; i < 4; ++i)
#pragma unroll
        for (int j = 0; j < 8; ++j) acc[i][j] += av[i] * bv[j];
    }
    __syncthreads();
  }
#pragma unroll
  for (int i = 0; i < 4; ++i) {
    int r = r0 + tr * 4 + i;
    int bb_ = r >> 8, s = r & 255;
    float* dst = xz + ((size_t)(d * 64 + bb_) * 256 + s) * 1024 + n0 + tc * 8;
    float4 o0 = {acc[i][0], acc[i][1], acc[i][2], acc[i][3]};
    float4 o1 = {acc[i][4], acc[i][5], acc[i][6], acc[i][7]};
    *(float4*)dst = o0;
    *(float4*)(dst + 4) = o1;
  }
}

// ---------------- kernel 3: LSTM recurrence, 2 seqs/CU + explicit U stream ----------------
// 64 blocks x 512 threads. Block = (dir, g): seqs seq0=dir*64+2g, seq0+1 share U.
// Thread owns cols colA=tid, colB=tid+512 for BOTH seqs (4 acc chains).
// U pairs 0..31 in LDS (128 KB, b128 reads); pairs 32..127 streamed from L2
// every step in 6 double-buffered chunks of fully-coalesced dwordx4 loads
// (1 KB/wave/inst; streamed working set 768 KB/XCD stays L2-resident).
// Register demand ~108 < the 128 cap the allocator always picks => no spill.
__global__ __launch_bounds__(512)
void lstm_seq(const float* __restrict__ xz, const u32* __restrict__ upk,
              const uint4* __restrict__ ustr, float* __restrict__ h_out) {
  const int bid = blockIdx.x;          // 0..63
  const int dir = bid >> 5;
  const int g   = bid & 31;
  const int b0  = 2 * g;
  const int seq0 = dir * 64 + b0;
  const int tid = threadIdx.x;
  const int colA = tid, colB = tid + 512;

  __shared__ uint4 ul[16][512];               // U pairs 0..31 (A rows 0..7, B rows 8..15), 128 KB
  __shared__ float zbuf[2][1024];             // 8 KB
  __shared__ __align__(16) u32 h2[2][128];    // h packed f16 pairs per seq, 1 KB

  // --- stage U pairs 0..31 into LDS ---
  const u32* ub = upk + (size_t)dir * 32768;
#pragma unroll
  for (int q = 0; q < 8; ++q) {
    uint4 va, vb;
    va.x = ub[(size_t)(4 * q + 0) * 1024 + colA];
    va.y = ub[(size_t)(4 * q + 1) * 1024 + colA];
    va.z = ub[(size_t)(4 * q + 2) * 1024 + colA];
    va.w = ub[(size_t)(4 * q + 3) * 1024 + colA];
    vb.x = ub[(size_t)(4 * q + 0) * 1024 + colB];
    vb.y = ub[(size_t)(4 * q + 1) * 1024 + colB];
    vb.z = ub[(size_t)(4 * q + 2) * 1024 + colB];
    vb.w = ub[(size_t)(4 * q + 3) * 1024 + colB];
    ul[q][tid] = va;
    ul[8 + q][tid] = vb;
  }
  if (tid < 256) ((u32*)h2)[tid] = 0u;

  const uint4* us = ustr + (size_t)dir * 6 * 4 * 1024;
  const float* xzp0 = xz + (size_t)seq0 * 262144;
  const float* xzp1 = xzp0 + 262144;
  float* hop0 = h_out + (size_t)b0 * 131072 + dir * 256 + tid;   // deref only tid<256
  float* hop1 = hop0 + 131072;
  float c0 = 0.0f, c1 = 0.0f;
  __syncthreads();

  const int sfirst = dir ? 255 : 0;
  float xA0 = xzp0[(size_t)sfirst * 1024 + colA];
  float xB0 = xzp0[(size_t)sfirst * 1024 + colB];
  float xA1 = xzp1[(size_t)sfirst * 1024 + colA];
  float xB1 = xzp1[(size_t)sfirst * 1024 + colB];

  for (int t = 0; t < 256; ++t) {
    const int scur  = dir ? (255 - t) : t;
    const int snext = (t < 255) ? (dir ? (254 - t) : (t + 1)) : sfirst;

    // ---- issue stream chunk 0 (pairs 32..47) ----
    uint4 sA[2][4], sB[2][4];
#pragma unroll
    for (int q = 0; q < 4; ++q) {
      sA[0][q] = us[(size_t)q * 1024 + colA];
      sB[0][q] = us[(size_t)q * 1024 + colB];
    }

    float aA0 = xA0, aB0 = xB0, aA1 = xA1, aB1 = xB1;
    // ---- LDS-resident pairs 0..31 (covers chunk-0 L2 latency) ----
#pragma unroll
    for (int q = 0; q < 8; ++q) {
      uint4 h0 = *(const uint4*)&h2[0][4 * q];
      uint4 h1 = *(const uint4*)&h2[1][4 * q];
      uint4 va = ul[q][tid];
      uint4 vb = ul[8 + q][tid];
      aA0 = FDOT2(H2(h0.x), H2(va.x), aA0); aA0 = FDOT2(H2(h0.y), H2(va.y), aA0);
      aA0 = FDOT2(H2(h0.z), H2(va.z), aA0); aA0 = FDOT2(H2(h0.w), H2(va.w), aA0);
      aB0 = FDOT2(H2(h0.x), H2(vb.x), aB0); aB0 = FDOT2(H2(h0.y), H2(vb.y), aB0);
      aB0 = FDOT2(H2(h0.z), H2(vb.z), aB0); aB0 = FDOT2(H2(h0.w), H2(vb.w), aB0);
      aA1 = FDOT2(H2(h1.x), H2(va.x), aA1); aA1 = FDOT2(H2(h1.y), H2(va.y), aA1);
      aA1 = FDOT2(H2(h1.z), H2(va.z), aA1); aA1 = FDOT2(H2(h1.w), H2(va.w), aA1);
      aB1 = FDOT2(H2(h1.x), H2(vb.x), aB1); aB1 = FDOT2(H2(h1.y), H2(vb.y), aB1);
      aB1 = FDOT2(H2(h1.z), H2(vb.z), aB1); aB1 = FDOT2(H2(h1.w), H2(vb.w), aB1);
    }
    // ---- streamed pairs 32..127, 6 chunks, 1-deep prefetch ----
#pragma unroll
    for (int cc = 0; cc < 6; ++cc) {
      const int cur = cc & 1, nxt = cur ^ 1;
      if (cc < 5) {
#pragma unroll
        for (int q = 0; q < 4; ++q) {
          sA[nxt][q] = us[(size_t)((cc + 1) * 4 + q) * 1024 + colA];
          sB[nxt][q] = us[(size_t)((cc + 1) * 4 + q) * 1024 + colB];
        }
      }
#pragma unroll
      for (int q = 0; q < 4; ++q) {
        const int pb = 32 + 16 * cc + 4 * q;
        uint4 h0 = *(const uint4*)&h2[0][pb];
        uint4 h1 = *(const uint4*)&h2[1][pb];
        uint4 va = sA[cur][q];
        uint4 vb = sB[cur][q];
        aA0 = FDOT2(H2(h0.x), H2(va.x), aA0); aA0 = FDOT2(H2(h0.y), H2(va.y), aA0);
        aA0 = FDOT2(H2(h0.z), H2(va.z), aA0); aA0 = FDOT2(H2(h0.w), H2(va.w), aA0);
        aB0 = FDOT2(H2(h0.x), H2(vb.x), aB0); aB0 = FDOT2(H2(h0.y), H2(vb.y), aB0);
        aB0 = FDOT2(H2(h0.z), H2(vb.z), aB0); aB0 = FDOT2(H2(h0.w), H2(vb.w), aB0);
        aA1 = FDOT2(H2(h1.x), H2(va.x), aA1); aA1 = FDOT2(H2(h1.y), H2(va.y), aA1);
        aA1 = FDOT2(H2(h1.z), H2(va.z), aA1); aA1 = FDOT2(H2(h1.w), H2(va.w), aA1);
        aB1 = FDOT2(H2(h1.x), H2(vb.x), aB1); aB1 = FDOT2(H2(h1.y), H2(vb.y), aB1);
        aB1 = FDOT2(H2(h1.z), H2(vb.z), aB1); aB1 = FDOT2(H2(h1.w), H2(vb.w), aB1);
      }
    }
    zbuf[0][colA] = aA0; zbuf[0][colB] = aB0;
    zbuf[1][colA] = aA1; zbuf[1][colB] = aB1;
    // prefetch next step's xz (overlaps barrier + gate phase)
    float nA0 = xzp0[(size_t)snext * 1024 + colA];
    float nB0 = xzp0[(size_t)snext * 1024 + colB];
    float nA1 = xzp1[(size_t)snext * 1024 + colA];
    float nB1 = xzp1[(size_t)snext * 1024 + colB];
    __syncthreads();

    if (tid < 256) {
      float zi = zbuf[0][tid], zf = zbuf[0][tid + 256];
      float zg = zbuf[0][tid + 512], zo = zbuf[0][tid + 768];
      c0 = sigf(zf) * c0 + sigf(zi) * tanhf_fast(zg);
      float h0v = sigf(zo) * tanhf_fast(c0);
      hop0[(size_t)scur * 512] = h0v;
      ((_Float16*)&h2[0][0])[tid] = (_Float16)h0v;
      zi = zbuf[1][tid]; zf = zbuf[1][tid + 256];
      zg = zbuf[1][tid + 512]; zo = zbuf[1][tid + 768];
      c1 = sigf(zf) * c1 + sigf(zi) * tanhf_fast(zg);
      float h1v = sigf(zo) * tanhf_fast(c1);
      hop1[(size_t)scur * 512] = h1v;
      ((_Float16*)&h2[1][0])[tid] = (_Float16)h1v;
    }
    __syncthreads();
    xA0 = nA0; xB0 = nB0; xA1 = nA1; xB1 = nB1;
  }
}

// ---------------- kernel 4: logits = h @ W_dense + b_dense ----------------
__global__ __launch_bounds__(256, 4)
void logits_k(const float* __restrict__ h_out, const float* __restrict__ Wd,
              const float* __restrict__ bd, float* __restrict__ out) {
  __shared__ float Ws[512 * 9];
  __shared__ float bs[16];
  const int tid = threadIdx.x;
  for (int i = tid; i < 4608; i += 256) Ws[i] = Wd[i];
  if (tid < 9) bs[tid] = bd[tid];
  __syncthreads();
  const int w = tid >> 6, lane = tid & 63;
  const int r0 = blockIdx.x * 16 + w * 4;
  for (int rr = 0; rr < 4; ++rr) {
    const int r = r0 + rr;
    const float* hp = h_out + (size_t)r * 512 + lane * 8;
    float4 h0 = *(const float4*)hp;
    float4 h1 = *(const float4*)(hp + 4);
    float hv[8] = {h0.x, h0.y, h0.z, h0.w, h1.x, h1.y, h1.z, h1.w};
    float outv = 0.0f;
#pragma unroll
    for (int l = 0; l < 9; ++l) {
      float p = 0.0f;
#pragma unroll
      for (int uu = 0; uu < 8; ++uu) p += hv[uu] * Ws[(lane * 8 + uu) * 9 + l];
      for (int off = 32; off; off >>= 1) p += __shfl_xor(p, off, 64);
      if (lane == l) outv = p;
    }
    if (lane < 9) out[(size_t)r * 9 + lane] = outv + bs[lane];
  }
}

// ---------------- kernel 5: CRF log-likelihood ----------------
__global__ void crf_k(const float* __restrict__ logits, const int* __restrict__ label,
                      const int* __restrict__ mask, const float* __restrict__ trans,
                      float* __restrict__ out_ll, float* __restrict__ out_trans) {
  const int b = blockIdx.x;
  const int lane = threadIdx.x;
  int cnt = 0;
#pragma unroll
  for (int q = 0; q < 4; ++q) cnt += (mask[b * 256 + lane + q * 64] != 0) ? 1 : 0;
  for (int off = 32; off; off >>= 1) cnt += __shfl_xor(cnt, off, 64);
  const int len = cnt;
  float un = 0.0f;
#pragma unroll
  for (int q = 0; q < 4; ++q) {
    int s = lane + q * 64;
    if (s < len) un += logits[((size_t)b * 256 + s) * 9 + label[b * 256 + s]];
  }
  for (int off = 32; off; off >>= 1) un += __shfl_xor(un, off, 64);
  float bin = 0.0f;
#pragma unroll
  for (int q = 0; q < 4; ++q) {
    int s = lane + q * 64;
    if (s < 255 && s < len - 1)
      bin += trans[label[b * 256 + s] * 9 + label[b * 256 + s + 1]];
  }
  for (int off = 32; off; off >>= 1) bin += __shfl_xor(bin, off, 64);
  float alpha = (lane < 9) ? logits[((size_t)b * 256) * 9 + lane] : -INFINITY;
  float tcol[9];
  if (lane < 9) {
#pragma unroll
    for (int i = 0; i < 9; ++i) tcol[i] = trans[i * 9 + lane];
  }
  for (int t = 1; t < 256; ++t) {
    float a[9];
#pragma unroll
    for (int i = 0; i < 9; ++i) a[i] = __shfl(alpha, i, 64);
    if (lane < 9) {
      float mx = a[0] + tcol[0];
#pragma unroll
      for (int i = 1; i < 9; ++i) mx = fmaxf(mx, a[i] + tcol[i]);
      float ssum = 0.0f;
#pragma unroll
      for (int i = 0; i < 9; ++i) ssum += __expf(a[i] + tcol[i] - mx);
      float nw = mx + __logf(ssum) + logits[((size_t)b * 256 + t) * 9 + lane];
      if (t < len) alpha = nw;
    }
  }
  float mx = alpha;
  for (int off = 32; off; off >>= 1) mx = fmaxf(mx, __shfl_xor(mx, off, 64));
  float e = __expf(alpha - mx);
  for (int off = 32; off; off >>= 1) e += __shfl_xor(e, off, 64);
  if (lane == 0) out_ll[b] = un + bin - (mx + __logf(e));
  if (b == 0) {
    for (int i = lane; i < 81; i += 64) out_trans[i] = trans[i];
  }
}

// ---------------- launch ----------------
extern "C" void kernel_launch(void* const* d_in, const int* in_sizes, int n_in,
                              void* d_out, int out_size, void* d_ws, size_t ws_size,
                              hipStream_t stream) {
  (void)in_sizes; (void)n_in; (void)out_size; (void)ws_size;
  const int*   inputs = (const int*)d_in[0];
  const int*   amask  = (const int*)d_in[1];
  const int*   label  = (const int*)d_in[2];
  const float* emb    = (const float*)d_in[3];
  const float* Wf     = (const float*)d_in[4];
  const float* Uf     = (const float*)d_in[5];
  const float* bf     = (const float*)d_in[6];
  const float* Wb     = (const float*)d_in[7];
  const float* Ub     = (const float*)d_in[8];
  const float* bb     = (const float*)d_in[9];
  const float* Wd     = (const float*)d_in[10];
  const float* bd     = (const float*)d_in[11];
  const float* trans  = (const float*)d_in[12];

  char* ws = (char*)d_ws;
  float* xz    = (float*)(ws + XZ_OFF);
  float* h_out = (float*)(ws + H_OFF);
  u32*   upk   = (u32*)(ws + UPK_OFF);
  u32*   ustr  = (u32*)(ws + USTR_OFF);

  float* out      = (float*)d_out;
  float* out_ll   = out + (size_t)Bn * Sn * Ln;        // 147456
  float* out_tr   = out_ll + Bn;                       // 147520

  pack_u<<<1024, 256, 0, stream>>>(Uf, Ub, upk, ustr);
  xz_gemm<<<dim3(256, 16), 256, 0, stream>>>(inputs, emb, Wf, bf, Wb, bb, xz);
  lstm_seq<<<64, 512, 0, stream>>>(xz, upk, (const uint4*)ustr, h_out);
  logits_k<<<1024, 256, 0, stream>>>(h_out, Wd, bd, out);
  crf_k<<<64, 64, 0, stream>>>(out, label, amask, trans, out_ll, out_tr);
}